// Round 3
// baseline (10885.683 us; speedup 1.0000x reference)
//
#include <hip/hip_runtime.h>
#include <hip/hip_bf16.h>
#include <stdint.h>

// ---------------------------------------------------------------------------
// LowRankLSTM  (SEQ=512, BS=64, IN=1024, HID=1024, RANK=256)
//
// Plan:
//   1. Convert weights to bf16; transpose B-operands so GEMM fragment loads
//      are contiguous (B^T layout, 8 consecutive K elems per lane). x is read
//      directly as f32 by the GEMM (converted in registers while staging).
//   2. Precompute full recurrent matrices Wrt[c][k] (c = h*4+gate, transposed)
//      = (U_h @ V_h)^T = V_h^T @ U_h^T via GEMM.
//   3. Precompute input projections xp[t][b][h*4+g] = ((x@U_i)@V_i) bf16.
//   4. 512 per-step kernels: fused (h @ W_rec) MFMA GEMM + LSTM cell.
//      Kernel boundary provides the grid-wide barrier (no coherence games).
// ---------------------------------------------------------------------------

typedef __attribute__((ext_vector_type(8))) short short8;   // 8 x bf16
typedef __attribute__((ext_vector_type(4))) float f32x4;

#define MFMA16(a, b, c) __builtin_amdgcn_mfma_f32_16x16x32_bf16((a), (b), (c), 0, 0, 0)

__device__ inline unsigned short f2bf(float f) {
  union { float f; unsigned int u; } v; v.f = f;
  unsigned int r = v.u + 0x7fffu + ((v.u >> 16) & 1u);  // RNE
  return (unsigned short)(r >> 16);
}
__device__ inline float bf2f(unsigned short u) {
  union { unsigned int u; float f; } v; v.u = ((unsigned int)u) << 16; return v.f;
}
__device__ inline float sigmoidf_(float x) {
  return 1.f / (1.f + __expf(-x));
}
__device__ inline float tanhf_(float x) {
  float cx = fminf(fmaxf(x, -15.f), 15.f);
  float e = __expf(2.f * cx);
  return (e - 1.f) / (e + 1.f);
}

// --------------------------- small prep kernels ----------------------------

__global__ __launch_bounds__(256) void convert_f32_bf16(
    const float* __restrict__ src, unsigned short* __restrict__ dst, int n) {
  int i = (blockIdx.x * 256 + threadIdx.x) * 4;
  if (i < n) {
    float4 v = *(const float4*)&src[i];
    ushort4 o;
    o.x = f2bf(v.x); o.y = f2bf(v.y); o.z = f2bf(v.z); o.w = f2bf(v.w);
    *(ushort4*)&dst[i] = o;
  }
}

// dst[c][r] = bf16(src[r][c]);  src is R x C row-major
__global__ __launch_bounds__(256) void transpose_f32_bf16(
    const float* __restrict__ src, unsigned short* __restrict__ dst, int R, int C) {
  int idx = blockIdx.x * 256 + threadIdx.x;
  if (idx < R * C) {
    int r = idx / C, c = idx - r * C;
    dst[(size_t)c * R + r] = f2bf(src[idx]);
  }
}

// --------------------------- tiled bf16 GEMM -------------------------------
// C[m*ldc + n*cstride + coff] = bf16( A[M x K] @ (BT[N x K])^T )
// M%128==0, N%128==0, K%64==0.  128x128 tile, BK=64, 4 waves (2x2 of 64x64).
// AF32: A operand is f32 row-major, converted to bf16 in registers.

template <bool AF32>
__device__ inline short8 load_a8(const void* A, size_t row, int K, int k) {
  if constexpr (AF32) {
    const float* a = (const float*)A + row * (size_t)K + k;
    float4 f0 = *(const float4*)a;
    float4 f1 = *(const float4*)(a + 4);
    short8 r;
    r[0] = (short)f2bf(f0.x); r[1] = (short)f2bf(f0.y);
    r[2] = (short)f2bf(f0.z); r[3] = (short)f2bf(f0.w);
    r[4] = (short)f2bf(f1.x); r[5] = (short)f2bf(f1.y);
    r[6] = (short)f2bf(f1.z); r[7] = (short)f2bf(f1.w);
    return r;
  } else {
    return *(const short8*)((const unsigned short*)A + row * (size_t)K + k);
  }
}

template <bool AF32>
__global__ __launch_bounds__(256) void gemm_bf16(
    const void* __restrict__ A, const unsigned short* __restrict__ BT,
    unsigned short* __restrict__ C, int M, int N, int K,
    int ldc, int cstride, int coff) {
  __shared__ unsigned short As[128 * 64];
  __shared__ unsigned short Bs[128 * 64];

  const int tid = threadIdx.x;
  const int m0 = blockIdx.y * 128;
  const int n0 = blockIdx.x * 128;
  const int w = tid >> 6, l = tid & 63;
  const int wm = w >> 1, wn = w & 1;
  const int lr = l & 15, lk = (l >> 4) * 8;

  const int srow = tid >> 3;          // 0..31
  const int sseg = (tid & 7) * 8;     // k-offset in elements

  f32x4 acc[4][4] = {};

  short8 av[4], bv[4];
#pragma unroll
  for (int p = 0; p < 4; ++p) {
    av[p] = load_a8<AF32>(A, m0 + p * 32 + srow, K, sseg);
    bv[p] = *(const short8*)(BT + (size_t)(n0 + p * 32 + srow) * K + sseg);
  }

  for (int k0 = 0; k0 < K; k0 += 64) {
    __syncthreads();   // previous tile's compute done
#pragma unroll
    for (int p = 0; p < 4; ++p) {
      *(short8*)&As[(p * 32 + srow) * 64 + sseg] = av[p];
      *(short8*)&Bs[(p * 32 + srow) * 64 + sseg] = bv[p];
    }
    __syncthreads();   // LDS ready
    if (k0 + 64 < K) {
#pragma unroll
      for (int p = 0; p < 4; ++p) {
        av[p] = load_a8<AF32>(A, m0 + p * 32 + srow, K, k0 + 64 + sseg);
        bv[p] = *(const short8*)(BT + (size_t)(n0 + p * 32 + srow) * K + k0 + 64 + sseg);
      }
    }
#pragma unroll
    for (int kk = 0; kk < 2; ++kk) {
      const int ko = kk * 32 + lk;
      short8 a[4], b[4];
#pragma unroll
      for (int i = 0; i < 4; ++i)
        a[i] = *(const short8*)&As[(wm * 64 + i * 16 + lr) * 64 + ko];
#pragma unroll
      for (int j = 0; j < 4; ++j)
        b[j] = *(const short8*)&Bs[(wn * 64 + j * 16 + lr) * 64 + ko];
#pragma unroll
      for (int i = 0; i < 4; ++i)
#pragma unroll
        for (int j = 0; j < 4; ++j)
          acc[i][j] = MFMA16(a[i], b[j], acc[i][j]);
    }
  }

  // epilogue: C/D layout col = lane&15, row = (lane>>4)*4 + reg
#pragma unroll
  for (int i = 0; i < 4; ++i) {
#pragma unroll
    for (int j = 0; j < 4; ++j) {
      const int rb = m0 + wm * 64 + i * 16 + (l >> 4) * 4;
      const int cb = n0 + wn * 64 + j * 16 + lr;
#pragma unroll
      for (int r = 0; r < 4; ++r)
        C[(size_t)(rb + r) * ldc + (size_t)cb * cstride + coff] = f2bf(acc[i][j][r]);
    }
  }
}

// --------------------------- per-step LSTM kernel --------------------------
// grid = 64 WGs x 256 threads.  WG n owns hidden units [n*16, n*16+16), i.e.
// columns [n*64, n*64+64) of the gate-interleaved 4096-wide space (c = h*4+g).
// pre[b][c] = hprev[64x1024]bf16 @ Wrt^T  (Wrt[c][k] row-major, contiguous k).
// Then fused LSTM cell; writes h_t (f32 -> d_out, bf16 -> ping-pong buffer).

__global__ __launch_bounds__(256) void lstm_step(
    const unsigned short* __restrict__ Wrt,   // [4096][1024] bf16
    const unsigned short* __restrict__ xp_t,  // [64][4096]   bf16
    const unsigned short* __restrict__ hprev, // [64][1024]   bf16 (unused t==0)
    unsigned short* __restrict__ hnext,       // [64][1024]   bf16
    const float* __restrict__ bi, const float* __restrict__ bf_,
    const float* __restrict__ bg, const float* __restrict__ bo,
    float* __restrict__ cstate,               // [64][1024] f32
    float* __restrict__ out_h,                // d_out + t*65536
    float* __restrict__ out_hT, float* __restrict__ out_cT,
    int t) {
  __shared__ float pre[64 * 64];

  const int tid = threadIdx.x;
  const int w = tid >> 6, l = tid & 63;
  const int c0 = blockIdx.x * 64;
  const int mr = (w >> 1) * 32;              // batch-row base for this wave
  const int nc = c0 + (w & 1) * 32;          // column base for this wave
  const int lr = l & 15, lk = (l >> 4) * 8;

  f32x4 acc[2][2] = {};

  if (t > 0) {
#pragma unroll 2
    for (int k = 0; k < 1024; k += 32) {
      short8 a0 = *(const short8*)&hprev[(mr + lr) * 1024 + k + lk];
      short8 a1 = *(const short8*)&hprev[(mr + 16 + lr) * 1024 + k + lk];
      short8 b0 = *(const short8*)&Wrt[(size_t)(nc + lr) * 1024 + k + lk];
      short8 b1 = *(const short8*)&Wrt[(size_t)(nc + 16 + lr) * 1024 + k + lk];
      acc[0][0] = MFMA16(a0, b0, acc[0][0]);
      acc[0][1] = MFMA16(a0, b1, acc[0][1]);
      acc[1][0] = MFMA16(a1, b0, acc[1][0]);
      acc[1][1] = MFMA16(a1, b1, acc[1][1]);
    }
  }

  // stage pre-activations to LDS: pre[batch][local col]
#pragma unroll
  for (int i = 0; i < 2; ++i)
#pragma unroll
    for (int j = 0; j < 2; ++j)
#pragma unroll
      for (int r = 0; r < 4; ++r)
        pre[(mr + i * 16 + (l >> 4) * 4 + r) * 64 + (w & 1) * 32 + j * 16 + lr] =
            acc[i][j][r];
  __syncthreads();

  // fused LSTM cell: 1024 (b,h) cells per WG, 4 per thread
#pragma unroll
  for (int rep = 0; rep < 4; ++rep) {
    const int cell = rep * 256 + tid;        // 0..1023
    const int bb = cell >> 4;                // batch 0..63
    const int hh = cell & 15;                // local hidden 0..15
    const int hid = (c0 >> 2) + hh;          // global hidden unit

    float4 p = *(const float4*)&pre[bb * 64 + hh * 4];
    ushort4 xq = *(const ushort4*)&xp_t[bb * 4096 + c0 + hh * 4];

    float pi = p.x + bf2f(xq.x) + bi[hid];
    float pf = p.y + bf2f(xq.y) + bf_[hid];
    float pg = p.z + bf2f(xq.z) + bg[hid];
    float po = p.w + bf2f(xq.w) + bo[hid];

    float ig = sigmoidf_(pi);
    float fg = sigmoidf_(pf);
    float gg = tanhf_(pg);
    float og = sigmoidf_(po);

    float cold = (t == 0) ? 0.f : cstate[bb * 1024 + hid];
    float cn = fg * cold + ig * gg;
    float hn = og * tanhf_(cn);

    cstate[bb * 1024 + hid] = cn;
    out_h[bb * 1024 + hid] = hn;
    hnext[bb * 1024 + hid] = f2bf(hn);
    if (t == 511) {
      out_hT[bb * 1024 + hid] = hn;
      out_cT[bb * 1024 + hid] = cn;
    }
  }
}

// ------------------------------- launcher ----------------------------------

extern "C" void kernel_launch(void* const* d_in, const int* in_sizes, int n_in,
                              void* d_out, int out_size, void* d_ws, size_t ws_size,
                              hipStream_t stream) {
  const float* x = (const float*)d_in[0];
  // weight order: ii, hi, if_, hf, ig, hg, io, ho  (U then V each)
  const float* WU[8]; const float* WV[8];
  for (int i = 0; i < 8; ++i) {
    WU[i] = (const float*)d_in[1 + 2 * i];
    WV[i] = (const float*)d_in[2 + 2 * i];
  }
  const int IGATE[4] = {0, 2, 4, 6};  // input-side:  ii, if_, ig, io
  const int HGATE[4] = {1, 3, 5, 7};  // hidden-side: hi, hf, hg, ho
  const float* bi = (const float*)d_in[17];
  const float* bf_ = (const float*)d_in[18];
  const float* bg = (const float*)d_in[19];
  const float* bo = (const float*)d_in[20];

  // ---- workspace layout (bytes), total ~288.5 MB ----
  char* ws = (char*)d_ws;
  const size_t OFF_UTI = 0;                         //  2,097,152  4x U_i^T (256x1024)
  const size_t OFF_VTI = OFF_UTI + 2097152;         //  2,097,152  4x V_i^T (1024x256)
  const size_t OFF_UBH = OFF_VTI + 2097152;         //  2,097,152  4x U_h bf16 (1024x256)
  const size_t OFF_VTH = OFF_UBH + 2097152;         //  2,097,152  4x V_h^T (1024x256)
  const size_t OFF_P   = OFF_VTH + 2097152;         // 16,777,216  P (32768x256) bf16
  const size_t OFF_XP  = OFF_P + 16777216;          // 268,435,456 xp (512x64x4096) bf16
  const size_t OFF_WRT = OFF_XP + 268435456;        //  8,388,608  Wrt (4096x1024) bf16
  const size_t OFF_HPP = OFF_WRT + 8388608;         //    262,144  h ping-pong 2x(64x1024) bf16
  const size_t OFF_CST = OFF_HPP + 262144;          //    262,144  c state (64x1024) f32

  unsigned short* uti = (unsigned short*)(ws + OFF_UTI);
  unsigned short* vti = (unsigned short*)(ws + OFF_VTI);
  unsigned short* ubh = (unsigned short*)(ws + OFF_UBH);
  unsigned short* vth = (unsigned short*)(ws + OFF_VTH);
  unsigned short* pbuf = (unsigned short*)(ws + OFF_P);
  unsigned short* xp = (unsigned short*)(ws + OFF_XP);
  unsigned short* wrt = (unsigned short*)(ws + OFF_WRT);
  unsigned short* hpp = (unsigned short*)(ws + OFF_HPP);
  float* cst = (float*)(ws + OFF_CST);
  float* out = (float*)d_out;

  // 1. weight conversions / transposes
  for (int g = 0; g < 4; ++g) {
    transpose_f32_bf16<<<1024, 256, 0, stream>>>(WU[IGATE[g]], uti + g * 262144, 1024, 256);
    transpose_f32_bf16<<<1024, 256, 0, stream>>>(WV[IGATE[g]], vti + g * 262144, 256, 1024);
    convert_f32_bf16<<<256, 256, 0, stream>>>(WU[HGATE[g]], ubh + g * 262144, 262144);
    transpose_f32_bf16<<<1024, 256, 0, stream>>>(WV[HGATE[g]], vth + g * 262144, 256, 1024);
  }

  // 2. Wrt[h*4+g][k] = (U_h @ V_h)[k][h] :  V_h^T (1024x256) @ U_h^T, BT = U_h
  for (int g = 0; g < 4; ++g) {
    gemm_bf16<false><<<dim3(8, 8), 256, 0, stream>>>(
        vth + g * 262144, ubh + g * 262144, wrt,
        1024, 1024, 256, 4096, 1, g * 1024);
  }

  // 3. input projections: P = x @ U_i ; xp[.,h*4+g] = P @ V_i
  for (int g = 0; g < 4; ++g) {
    gemm_bf16<true><<<dim3(2, 256), 256, 0, stream>>>(
        x, uti + g * 262144, pbuf, 32768, 256, 1024, 256, 1, 0);
    gemm_bf16<false><<<dim3(8, 256), 256, 0, stream>>>(
        pbuf, vti + g * 262144, xp, 32768, 1024, 256, 4096, 4, g);
  }

  // 4. recurrence: 512 fused step kernels (launch boundary = grid barrier)
  for (int t = 0; t < 512; ++t) {
    const unsigned short* hp = hpp + ((t & 1) ^ 1) * 65536;
    unsigned short* hn = hpp + (t & 1) * 65536;
    lstm_step<<<64, 256, 0, stream>>>(
        wrt, xp + (size_t)t * 262144, hp, hn,
        bi, bf_, bg, bo, cst,
        out + (size_t)t * 65536,
        out + 33554432, out + 33554432 + 65536, t);
  }
}